// Round 1
// baseline (1288.206 us; speedup 1.0000x reference)
//
#include <hip/hip_runtime.h>

// Llama4TextExperts: E=8 experts, H=2048, D=2048, 4096 tokens/expert.
// out = (up * silu(gate)) @ W2,  [gate|up] = x @ W1
// Strategy: convert everything to bf16 (threshold is bf16-scaled), pre-transpose
// weights to n-major so both MFMA operands are k-contiguous, then two
// m97-style global_load_lds MFMA GEMMs; SwiGLU fused into GEMM1 epilogue.

#define E_EXPERTS 8
#define HID 2048
#define TPE 4096  // tokens per expert

typedef __bf16 bf16_t;
typedef __bf16 bf16x4 __attribute__((ext_vector_type(4)));
typedef __bf16 bf16x8 __attribute__((ext_vector_type(8)));
typedef float f32x4 __attribute__((ext_vector_type(4)));

// async global->LDS, 16B per lane; dest = wave-uniform base + lane*16
#define GLOAD16(src, dst)                                               \
  __builtin_amdgcn_global_load_lds(                                     \
      (const __attribute__((address_space(1))) void*)(src),             \
      (__attribute__((address_space(3))) void*)(dst), 16, 0, 0)

// ---------------- pass 1: x f32 -> bf16 ----------------
__global__ void cvt_f32_bf16_kernel(const float* __restrict__ in,
                                    bf16_t* __restrict__ out, long n4) {
  long i = (long)blockIdx.x * blockDim.x + threadIdx.x;
  const long stride = (long)gridDim.x * blockDim.x;
  const float4* in4 = (const float4*)in;
  bf16x4* out4 = (bf16x4*)out;
  for (; i < n4; i += stride) {
    float4 v = in4[i];
    bf16x4 o = {(bf16_t)v.x, (bf16_t)v.y, (bf16_t)v.z, (bf16_t)v.w};
    out4[i] = o;
  }
}

// ------- pass 2: per-expert transpose+convert: W[K][N] f32 -> WT[N][K] bf16 -------
__global__ void transpose_cvt_kernel(const float* __restrict__ W,
                                     bf16_t* __restrict__ WT, int K, int N) {
  __shared__ float tile[64][65];
  const int e = blockIdx.z;
  const float* Wp = W + (size_t)e * K * N;
  bf16_t* Tp = WT + (size_t)e * N * K;
  const int n0 = blockIdx.x * 64, k0 = blockIdx.y * 64;
  const int rr = threadIdx.x >> 4;        // 0..15
  const int cc = (threadIdx.x & 15) * 4;  // 0..60
#pragma unroll
  for (int p = 0; p < 4; ++p) {
    const int k = rr + p * 16;
    float4 v = *(const float4*)(Wp + (size_t)(k0 + k) * N + n0 + cc);
    tile[k][cc + 0] = v.x;
    tile[k][cc + 1] = v.y;
    tile[k][cc + 2] = v.z;
    tile[k][cc + 3] = v.w;
  }
  __syncthreads();
#pragma unroll
  for (int p = 0; p < 4; ++p) {
    const int n = rr + p * 16;
    bf16x4 o;
#pragma unroll
    for (int j = 0; j < 4; ++j) o[j] = (bf16_t)tile[cc + j][n];
    *(bf16x4*)(Tp + (size_t)(n0 + n) * K + k0 + cc) = o;
  }
}

// ---------------- grouped GEMM (+ optional fused SwiGLU) ----------------
// A: [E][TPE][2048] bf16 (k-contiguous rows)
// B: [E][BN_total][2048] bf16 n-major (pre-transposed weights)
// FUSED:  dual-B (gate rows n, up rows 2048+n), Cout = act bf16 [E][TPE][2048]
// !FUSED: single-B, Cout = float [E][TPE][2048]
template <bool FUSED>
__global__ __launch_bounds__(256, 2) void moe_gemm_kernel(
    const bf16_t* __restrict__ A, const bf16_t* __restrict__ B,
    void* __restrict__ Cout) {
  constexpr int BM = 128, BN = 128, BK = 32, K = 2048;
  constexpr int BROWS = FUSED ? 256 : 128;
  constexpr int NT = K / BK;  // 64
  constexpr size_t A_EXP = (size_t)TPE * K;
  constexpr size_t B_EXP = (size_t)(FUSED ? 4096 : 2048) * K;

  __shared__ alignas(16) bf16_t As[2][BM][BK];
  __shared__ alignas(16) bf16_t Bs[2][BROWS][BK];

  const int e = blockIdx.z;
  const int n0 = blockIdx.x * BN;
  const int t0 = blockIdx.y * BM;
  const int tid = threadIdx.x;
  const int wid = tid >> 6, lane = tid & 63;
  const int wr = wid >> 1, wc = wid & 1;  // 2x2 wave grid, 64x64 per wave

  const bf16_t* Ae = A + (size_t)e * A_EXP + (size_t)t0 * K;
  const bf16_t* Be = B + (size_t)e * B_EXP;

  const int lr = lane >> 2;       // row within one 16-row (1 KiB) chunk
  const int lc = (lane & 3) * 8;  // 16B col chunk

  f32x4 accg[4][4] = {};
  f32x4 accu[4][4] = {};

  auto stage = [&](int kt, int nb) {
    const int k0 = kt * BK;
    // A tile: 8 KiB = 8 x 1KiB issues, 2 per wave
#pragma unroll
    for (int jj = 0; jj < 2; ++jj) {
      const int j = wid * 2 + jj;
      GLOAD16(Ae + (size_t)(j * 16 + lr) * K + (k0 + lc), &As[nb][j * 16][0]);
    }
    if constexpr (FUSED) {
      // gate rows (j 0..7) then up rows (j 8..15), 4 issues per wave
#pragma unroll
      for (int jj = 0; jj < 4; ++jj) {
        const int j = wid * 4 + jj;
        const int srow = (j >> 3) * 2048 + n0 + (j & 7) * 16 + lr;
        GLOAD16(Be + (size_t)srow * K + (k0 + lc), &Bs[nb][j * 16][0]);
      }
    } else {
#pragma unroll
      for (int jj = 0; jj < 2; ++jj) {
        const int j = wid * 2 + jj;
        GLOAD16(Be + (size_t)(n0 + j * 16 + lr) * K + (k0 + lc),
                &Bs[nb][j * 16][0]);
      }
    }
  };

  const int la = lane & 15, kg = (lane >> 4) * 8;

  auto compute = [&](int cb) {
    bf16x8 af[4], bg[4], bu[4];
#pragma unroll
    for (int m = 0; m < 4; ++m)
      af[m] = *(const bf16x8*)&As[cb][wr * 64 + m * 16 + la][kg];
#pragma unroll
    for (int n = 0; n < 4; ++n)
      bg[n] = *(const bf16x8*)&Bs[cb][wc * 64 + n * 16 + la][kg];
    if constexpr (FUSED) {
#pragma unroll
      for (int n = 0; n < 4; ++n)
        bu[n] = *(const bf16x8*)&Bs[cb][128 + wc * 64 + n * 16 + la][kg];
    }
#pragma unroll
    for (int m = 0; m < 4; ++m) {
#pragma unroll
      for (int n = 0; n < 4; ++n) {
        accg[m][n] = __builtin_amdgcn_mfma_f32_16x16x32_bf16(af[m], bg[n],
                                                             accg[m][n], 0, 0, 0);
        if constexpr (FUSED)
          accu[m][n] = __builtin_amdgcn_mfma_f32_16x16x32_bf16(
              af[m], bu[n], accu[m][n], 0, 0, 0);
      }
    }
  };

  stage(0, 0);
  __syncthreads();
  for (int kt = 0; kt < NT; ++kt) {
    if (kt + 1 < NT) stage(kt + 1, (kt + 1) & 1);
    compute(kt & 1);
    __syncthreads();  // drains gload_lds (vmcnt) + lgkm before buffer swap
  }

  // Epilogue. Verified C/D layout: row=(lane>>4)*4+r, col=lane&15.
  const int lg = lane >> 4;
  if constexpr (FUSED) {
    bf16_t* Cp = (bf16_t*)Cout + (size_t)e * A_EXP;
#pragma unroll
    for (int m = 0; m < 4; ++m)
#pragma unroll
      for (int n = 0; n < 4; ++n)
#pragma unroll
        for (int r = 0; r < 4; ++r) {
          const int row = t0 + wr * 64 + m * 16 + lg * 4 + r;
          const int col = n0 + wc * 64 + n * 16 + la;
          const float g = accg[m][n][r], u = accu[m][n][r];
          const float sv = 1.0f / (1.0f + __expf(-g));  // sigmoid
          Cp[(size_t)row * 2048 + col] = (bf16_t)(u * g * sv);
        }
  } else {
    float* Cp = (float*)Cout + (size_t)e * A_EXP;
#pragma unroll
    for (int m = 0; m < 4; ++m)
#pragma unroll
      for (int n = 0; n < 4; ++n)
#pragma unroll
        for (int r = 0; r < 4; ++r) {
          const int row = t0 + wr * 64 + m * 16 + lg * 4 + r;
          const int col = n0 + wc * 64 + n * 16 + la;
          Cp[(size_t)row * 2048 + col] = accg[m][n][r];
        }
  }
}

extern "C" void kernel_launch(void* const* d_in, const int* in_sizes, int n_in,
                              void* d_out, int out_size, void* d_ws,
                              size_t ws_size, hipStream_t stream) {
  const float* hs = (const float*)d_in[0];  // (32768, 2048)
  const float* w1 = (const float*)d_in[1];  // (8, 2048, 4096)
  const float* w2 = (const float*)d_in[2];  // (8, 2048, 2048)

  // ws layout (448 MiB total):
  //   xb  bf16 [32768][2048]        128 MiB @ 0
  //   w1t bf16 [8][4096][2048]      128 MiB @ 128M   (W1^T per expert)
  //   w2t bf16 [8][2048][2048]       64 MiB @ 256M   (W2^T per expert)
  //   act bf16 [8][4096][2048]      128 MiB @ 320M
  char* ws = (char*)d_ws;
  bf16_t* xb = (bf16_t*)(ws);
  bf16_t* w1t = (bf16_t*)(ws + (size_t)134217728);
  bf16_t* w2t = (bf16_t*)(ws + (size_t)268435456);
  bf16_t* act = (bf16_t*)(ws + (size_t)335544320);

  const long n4 = (long)E_EXPERTS * TPE * HID / 4;  // float4 count
  cvt_f32_bf16_kernel<<<2048, 256, 0, stream>>>(hs, xb, n4);
  transpose_cvt_kernel<<<dim3(64, 32, 8), 256, 0, stream>>>(w1, w1t, 2048, 4096);
  transpose_cvt_kernel<<<dim3(32, 32, 8), 256, 0, stream>>>(w2, w2t, 2048, 2048);
  moe_gemm_kernel<true><<<dim3(16, 32, 8), 256, 0, stream>>>(xb, w1t, (void*)act);
  moe_gemm_kernel<false><<<dim3(16, 32, 8), 256, 0, stream>>>(act, w2t, d_out);
}

// Round 2
// 1164.564 us; speedup vs baseline: 1.1062x; 1.1062x over previous
//
#include <hip/hip_runtime.h>

// Llama4TextExperts: E=8, H=2048, D=2048, 4096 tokens/expert.
// out = (up * silu(gate)) @ W2,  [gate|up] = x @ W1
// Round 2: 256x256 8-phase pipelined MFMA GEMM (counted vmcnt, XOR-swizzled
// LDS via pre-swizzled global_load_lds source), SwiGLU fused into GEMM1 via
// 16-col gate/up interleaved B-row remap at staging time.

#define E_EXPERTS 8
#define TPE 4096
#define KD 2048

typedef __bf16 bf16_t;
typedef __bf16 bf16x4 __attribute__((ext_vector_type(4)));
typedef __bf16 bf16x8 __attribute__((ext_vector_type(8)));
typedef float f32x4 __attribute__((ext_vector_type(4)));

#define GLOAD16(src, dst)                                               \
  __builtin_amdgcn_global_load_lds(                                     \
      (const __attribute__((address_space(1))) void*)(src),             \
      (__attribute__((address_space(3))) void*)(dst), 16, 0, 0)

// ---------------- pass 1: x f32 -> bf16 ----------------
__global__ void cvt_f32_bf16_kernel(const float* __restrict__ in,
                                    bf16_t* __restrict__ out, long n4) {
  long i = (long)blockIdx.x * blockDim.x + threadIdx.x;
  const long stride = (long)gridDim.x * blockDim.x;
  const float4* in4 = (const float4*)in;
  bf16x4* out4 = (bf16x4*)out;
  for (; i < n4; i += stride) {
    float4 v = in4[i];
    bf16x4 o = {(bf16_t)v.x, (bf16_t)v.y, (bf16_t)v.z, (bf16_t)v.w};
    out4[i] = o;
  }
}

// ------- pass 2: per-expert transpose+convert: W[K][N] f32 -> WT[N][K] bf16 -------
__global__ void transpose_cvt_kernel(const float* __restrict__ W,
                                     bf16_t* __restrict__ WT, int K, int N) {
  __shared__ float tile[64][65];
  const int e = blockIdx.z;
  const float* Wp = W + (size_t)e * K * N;
  bf16_t* Tp = WT + (size_t)e * N * K;
  const int n0 = blockIdx.x * 64, k0 = blockIdx.y * 64;
  const int rr = threadIdx.x >> 4;
  const int cc = (threadIdx.x & 15) * 4;
#pragma unroll
  for (int p = 0; p < 4; ++p) {
    const int k = rr + p * 16;
    float4 v = *(const float4*)(Wp + (size_t)(k0 + k) * N + n0 + cc);
    tile[k][cc + 0] = v.x;
    tile[k][cc + 1] = v.y;
    tile[k][cc + 2] = v.z;
    tile[k][cc + 3] = v.w;
  }
  __syncthreads();
#pragma unroll
  for (int p = 0; p < 4; ++p) {
    const int n = rr + p * 16;
    bf16x4 o;
#pragma unroll
    for (int j = 0; j < 4; ++j) o[j] = (bf16_t)tile[cc + j][n];
    *(bf16x4*)(Tp + (size_t)(n0 + n) * K + k0 + cc) = o;
  }
}

// ---------------- 256x256 8-phase grouped GEMM ----------------
// A: [E][4096][2048] bf16 row-major (k-contiguous)
// B: FUSED: w1t [E][4096][2048] (plain transpose; gate rows 0..2047, up
//           2048..4095), accessed through a 16-col interleave remap so the
//           GEMM's virtual n-rows alternate gate/up in 16-row blocks.
//    else:  w2t [E][2048][2048]
// C: FUSED: act bf16 [E][4096][2048] = up * silu(gate)
//    else:  out f32 [E][4096][2048]
//
// Per K-tile (BK=64) 4 phases; quadrants (qm,qn) of the wave's 128x64 output:
//   P1: read A[qm0](8) + B[qn0](4); stage (t+1).Ah0 | MFMA (0,0)
//   P2: read B[qn1](4);             stage (t+1).Ah1 | MFMA (0,1)
//   P3: read A[qm1](8);             stage (t+2).Bh0 | MFMA (1,1)
//   P4: (B qn0 kept in regs);       stage (t+2).Bh1 | vmcnt(4) | MFMA (1,0)
// Race-safety: A stages always hit the opposite-parity buffer; (t+2).B stages
// hit the resident buffer but only after P2-end barrier, by which point all
// waves' B reads (P1/P2, lgkm-waited before their MFMAs) completed.
#define MMA_QUAD(QM, QN, BF)                                                 \
  do {                                                                       \
    _Pragma("unroll") for (int kk = 0; kk < 2; ++kk) {                       \
      _Pragma("unroll") for (int m = 0; m < 4; ++m) {                        \
        _Pragma("unroll") for (int n = 0; n < 2; ++n) {                      \
          acc[(QM)*4 + m][(QN)*2 + n] =                                      \
              __builtin_amdgcn_mfma_f32_16x16x32_bf16(                       \
                  af[m][kk], BF[n][kk], acc[(QM)*4 + m][(QN)*2 + n], 0, 0, 0); \
        }                                                                    \
      }                                                                      \
    }                                                                        \
  } while (0)

template <bool FUSED, int NTN>
__global__ __launch_bounds__(512, 2) void moe_gemm8_kernel(
    const bf16_t* __restrict__ A, const bf16_t* __restrict__ Bm,
    void* __restrict__ Cout) {
  constexpr int NT = KD / 64;  // 32 K-tiles
  constexpr int NWG = E_EXPERTS * 16 * NTN;

  __shared__ alignas(16) bf16_t As[2][256][64];
  __shared__ alignas(16) bf16_t Bs[2][256][64];

  // bijective XCD swizzle (NWG % 8 == 0)
  int wg = blockIdx.x;
  wg = (wg & 7) * (NWG / 8) + (wg >> 3);
  const int e = wg / (16 * NTN);
  const int rem = wg % (16 * NTN);
  const int mt = rem / NTN, ntile = rem % NTN;
  const int t0 = mt * 256, n0 = ntile * 256;

  const int tid = threadIdx.x;
  const int wid = tid >> 6, lane = tid & 63;
  const int wr = wid >> 2, wc = wid & 3;  // 2(M) x 4(N) waves; 128x64 each

  const bf16_t* Ae = A + (size_t)e * TPE * KD + (size_t)t0 * KD;
  const bf16_t* Be = Bm + (size_t)e * (size_t)(FUSED ? 4096 : 2048) * KD;

  // staging lane constants: 8 rows x 8 chunks(16B) per gload; source chunk
  // pre-swizzled so LDS-linear write == XOR-swizzled layout.
  const int slr = lane >> 3;                 // row 0..7 within 8-row block
  const int sel = ((lane & 7) ^ slr) * 8;    // element offset (chunk^row)*8

  auto stageA = [&](int kt, int h) {
    const int ktw = (kt < NT) ? kt : kt - NT;
    const int k0 = ktw * 64;
    const int buf = kt & 1;
#pragma unroll
    for (int i = 0; i < 2; ++i) {
      const int r0 = h * 128 + wid * 16 + i * 8;
      GLOAD16(Ae + (size_t)(r0 + slr) * KD + k0 + sel, &As[buf][r0][0]);
    }
  };
  auto stageB = [&](int kt, int h) {
    const int ktw = (kt < NT) ? kt : kt - NT;
    const int k0 = ktw * 64;
    const int buf = kt & 1;
#pragma unroll
    for (int i = 0; i < 2; ++i) {
      const int r0 = h * 128 + wid * 16 + i * 8;
      const int R = n0 + r0 + slr;
      int srow;
      if constexpr (FUSED)
        srow = ((R >> 5) << 4) + (R & 15) + ((R >> 4) & 1) * 2048;
      else
        srow = R;
      GLOAD16(Be + (size_t)srow * KD + k0 + sel, &Bs[buf][r0][0]);
    }
  };

  const int la = lane & 15, kg4 = lane >> 4;

  f32x4 acc[8][4] = {};  // [m-frag 0..7][n-frag 0..3]
  bf16x8 af[4][2];       // current qm's A fragments [m][kk]
  bf16x8 b0[2][2];       // qn=0 B fragments [n][kk]
  bf16x8 b1[2][2];       // qn=1

  auto readA = [&](int buf, int qm) {
#pragma unroll
    for (int m = 0; m < 4; ++m) {
      const int row = wr * 128 + qm * 64 + m * 16 + la;
#pragma unroll
      for (int kk = 0; kk < 2; ++kk) {
        const int ch = ((kk * 4 + kg4) ^ (la & 7)) * 8;
        af[m][kk] = *(const bf16x8*)&As[buf][row][ch];
      }
    }
  };
  auto readB = [&](int buf, int qn, bf16x8 (&bf)[2][2]) {
#pragma unroll
    for (int n = 0; n < 2; ++n) {
      const int row = wc * 64 + qn * 32 + n * 16 + la;
#pragma unroll
      for (int kk = 0; kk < 2; ++kk) {
        const int ch = ((kk * 4 + kg4) ^ (la & 7)) * 8;
        bf[n][kk] = *(const bf16x8*)&Bs[buf][row][ch];
      }
    }
  };

#define LGKM0 asm volatile("s_waitcnt lgkmcnt(0)" ::: "memory")
#define VMC4 asm volatile("s_waitcnt vmcnt(4)" ::: "memory")
#define BAR __builtin_amdgcn_s_barrier()
#define PRIO1 __builtin_amdgcn_s_setprio(1)
#define PRIO0 __builtin_amdgcn_s_setprio(0)

  // prologue: tile0 (A+B) and tile1 (B only); drain tile0, keep tile1.B in flight
  stageA(0, 0); stageA(0, 1);
  stageB(0, 0); stageB(0, 1);
  stageB(1, 0); stageB(1, 1);
  VMC4;
  BAR;

  auto tile = [&](int kt, int buf) {
    // P1
    readA(buf, 0);
    readB(buf, 0, b0);
    stageA(kt + 1, 0);
    BAR; LGKM0;
    PRIO1; MMA_QUAD(0, 0, b0); PRIO0;
    BAR;
    // P2
    readB(buf, 1, b1);
    stageA(kt + 1, 1);
    BAR; LGKM0;
    PRIO1; MMA_QUAD(0, 1, b1); PRIO0;
    BAR;
    // P3
    readA(buf, 1);
    stageB(kt + 2, 0);
    BAR; LGKM0;
    PRIO1; MMA_QUAD(1, 1, b1); PRIO0;
    BAR;
    // P4
    stageB(kt + 2, 1);
    VMC4;
    BAR;
    PRIO1; MMA_QUAD(1, 0, b0); PRIO0;
    BAR;
  };

  for (int kt = 0; kt < NT; kt += 2) {
    tile(kt, 0);
    tile(kt + 1, 1);
  }

  // Epilogue. C/D layout: row=(lane>>4)*4+r, col=lane&15 (verified round 1).
  const int lg = lane >> 4;
  const int rbase = t0 + wr * 128;
  if constexpr (FUSED) {
    bf16_t* Cp = (bf16_t*)Cout + (size_t)e * TPE * KD;
    const int jb = (n0 + wc * 64) >> 1;  // even frag=gate, odd=up, same cols
#pragma unroll
    for (int m = 0; m < 8; ++m)
#pragma unroll
      for (int p = 0; p < 2; ++p)
#pragma unroll
        for (int r = 0; r < 4; ++r) {
          const int row = rbase + m * 16 + lg * 4 + r;
          const int col = jb + p * 16 + la;
          const float g = acc[m][2 * p][r], u = acc[m][2 * p + 1][r];
          const float s = 1.0f / (1.0f + __expf(-g));
          Cp[(size_t)row * KD + col] = (bf16_t)(u * g * s);
        }
  } else {
    float* Cp = (float*)Cout + (size_t)e * TPE * KD;
#pragma unroll
    for (int m = 0; m < 8; ++m)
#pragma unroll
      for (int n = 0; n < 4; ++n)
#pragma unroll
        for (int r = 0; r < 4; ++r) {
          const int row = rbase + m * 16 + lg * 4 + r;
          const int col = n0 + wc * 64 + n * 16 + la;
          Cp[(size_t)row * KD + col] = acc[m][n][r];
        }
  }
#undef LGKM0
#undef VMC4
#undef BAR
#undef PRIO1
#undef PRIO0
}

extern "C" void kernel_launch(void* const* d_in, const int* in_sizes, int n_in,
                              void* d_out, int out_size, void* d_ws,
                              size_t ws_size, hipStream_t stream) {
  const float* hs = (const float*)d_in[0];  // (32768, 2048)
  const float* w1 = (const float*)d_in[1];  // (8, 2048, 4096)
  const float* w2 = (const float*)d_in[2];  // (8, 2048, 2048)

  // ws layout (448 MiB, known-good):
  //   xb  bf16 [32768][2048]     128 MiB @ 0
  //   w1t bf16 [8][4096][2048]   128 MiB @ 128M  (plain W1^T per expert)
  //   w2t bf16 [8][2048][2048]    64 MiB @ 256M
  //   act bf16 [8][4096][2048]   128 MiB @ 320M
  char* ws = (char*)d_ws;
  bf16_t* xb = (bf16_t*)(ws);
  bf16_t* w1t = (bf16_t*)(ws + (size_t)134217728);
  bf16_t* w2t = (bf16_t*)(ws + (size_t)268435456);
  bf16_t* act = (bf16_t*)(ws + (size_t)335544320);

  const long n4 = (long)E_EXPERTS * TPE * KD / 4;
  cvt_f32_bf16_kernel<<<2048, 256, 0, stream>>>(hs, xb, n4);
  transpose_cvt_kernel<<<dim3(64, 32, 8), 256, 0, stream>>>(w1, w1t, 2048, 4096);
  transpose_cvt_kernel<<<dim3(32, 32, 8), 256, 0, stream>>>(w2, w2t, 2048, 2048);
  moe_gemm8_kernel<true, 16><<<2048, 512, 0, stream>>>(xb, w1t, (void*)act);
  moe_gemm8_kernel<false, 8><<<1024, 512, 0, stream>>>(act, w2t, d_out);
}